// Round 8
// baseline (79.671 us; speedup 1.0000x reference)
//
#include <hip/hip_runtime.h>

#define IO_DIM 64
#define WIDTH 16
#define HID 128
#define BS_ 1024                 // 64*16

// ws layout v2 (floats):
//   wT [64][16]  at    0..1024)   : wT[k][j] = w[j][k]
//   uT [64][16]  at 1024..2048)   : uT[d][j] = u[j][d] / 16
//   bb [16]      at 2048..2064)
//   nuw[16]      at 2064..2080)   : -uw[j] / 16

__device__ __forceinline__ float fast_tanh(float x) {
    float e = __expf(2.0f * x);
    return 1.0f - __fdividef(2.0f, e + 1.0f);
}

__global__ __launch_bounds__(128) void cnf_prep(
    const float* __restrict__ t, const float* __restrict__ W1,
    const float* __restrict__ b1, const float* __restrict__ W2,
    const float* __restrict__ b2, const float* __restrict__ W3,
    const float* __restrict__ b3, float* __restrict__ ws)
{
    __shared__ float h1[HID];
    __shared__ float h2[HID];
    __shared__ float su[64], sw[64];
    const int tid = threadIdx.x;

    h1[tid] = tanhf(W1[tid] * t[0] + b1[tid]);
    __syncthreads();

    {
        float s = b2[tid];
        const float4* W2v = (const float4*)(W2 + tid * HID);
        #pragma unroll 8
        for (int k = 0; k < HID / 4; ++k) {
            float4 wv = W2v[k];
            s = fmaf(wv.x, h1[4 * k + 0], s);
            s = fmaf(wv.y, h1[4 * k + 1], s);
            s = fmaf(wv.z, h1[4 * k + 2], s);
            s = fmaf(wv.w, h1[4 * k + 3], s);
        }
        h2[tid] = tanhf(s);
    }
    __syncthreads();

    const int b = blockIdx.x;
    if (b < 16) {
        // block b owns output row j=b of both u and w (64 elements each)
        const int half = tid >> 6;   // 0 -> u, 1 -> w
        const int i = tid & 63;      // element index (d or k)
        const int row = half * BS_ + b * 64 + i;
        float s = b3[row];
        const float4* W3v = (const float4*)(W3 + row * HID);
        #pragma unroll 8
        for (int k = 0; k < HID / 4; ++k) {
            float4 wv = W3v[k];
            s = fmaf(wv.x, h2[4 * k + 0], s);
            s = fmaf(wv.y, h2[4 * k + 1], s);
            s = fmaf(wv.z, h2[4 * k + 2], s);
            s = fmaf(wv.w, h2[4 * k + 3], s);
        }
        if (half == 0) {
            ws[1024 + i * 16 + b] = s * (1.0f / WIDTH);   // uT[d][j], scale folded
            su[i] = s;
        } else {
            ws[i * 16 + b] = s;                           // wT[k][j]
            sw[i] = s;
        }
        __syncthreads();
        if (tid < 64) {
            float p = su[tid] * sw[tid];
            #pragma unroll
            for (int m = 32; m >= 1; m >>= 1) p += __shfl_xor(p, m, 64);
            if (tid == 0) ws[2064 + b] = -p * (1.0f / WIDTH);   // nuw[b]
        }
    } else {
        if (tid < WIDTH) {
            const int row = 2 * BS_ + tid;
            float s = b3[row];
            const float4* W3v = (const float4*)(W3 + row * HID);
            #pragma unroll 8
            for (int k = 0; k < HID / 4; ++k) {
                float4 wv = W3v[k];
                s = fmaf(wv.x, h2[4 * k + 0], s);
                s = fmaf(wv.y, h2[4 * k + 1], s);
                s = fmaf(wv.z, h2[4 * k + 2], s);
                s = fmaf(wv.w, h2[4 * k + 3], s);
            }
            ws[2048 + tid] = s;   // bb
        }
    }
}

__global__ __launch_bounds__(64) void cnf_main(
    const float* __restrict__ z, const float* __restrict__ ws,
    float* __restrict__ dz, float* __restrict__ dlog, int n)
{
    // One wave per block. 16 KB wave-private tile; ZERO barriers (same-wave DS
    // ops are in-order — validated rounds 5-7). Tile holds z during phase 1,
    // then is reused in place as the dz transpose slice (proven round-6/7
    // geometry: full 128-B-line stores, conflict-free swizzles).
    __shared__ __align__(16) float4 ztile[64][16];

    const int l = threadIdx.x;            // lane 0..63
    const int base = blockIdx.x * 64;
    const int row = base + l;
    const bool valid = row < n;
    const int n16 = n * 16;

    // stage z: 16 fully-coalesced 1 KB loads -> swizzled ds_write.
    // lane l, instr i covers chunk g = i*64+l -> tile row i*4+(l>>4), col l&15.
    const float4* zv4 = (const float4*)z;
    #pragma unroll
    for (int i = 0; i < 16; ++i) {
        int g = base * 16 + i * 64 + l;
        g = min(g, n16 - 1);              // clamp: stay in bounds on last tile
        const float4 v = zv4[g];
        const int r = i * 4 + (l >> 4);
        const int c = l & 15;
        ztile[r][c ^ (r & 15)] = v;       // 8 words/bank floor
    }
    // (no barrier: wave-private; DS ops in order after implicit vm waits)

    // phase 1: a[j] = bb[j] + sum_k z[k] * wT[k][j]  (weights via uniform s_load)
    float a[WIDTH];
    #pragma unroll
    for (int j = 0; j < WIDTH; ++j) a[j] = ws[2048 + j];

    #pragma unroll
    for (int k4 = 0; k4 < 16; ++k4) {
        const float4 zv = ztile[l][k4 ^ (l & 15)];   // own row, swizzle-matched
        const float* wk = ws + k4 * 64;              // wT rows 4k4..4k4+3
        #pragma unroll
        for (int j = 0; j < WIDTH; ++j) a[j] = fmaf(zv.x, wk[j],      a[j]);
        #pragma unroll
        for (int j = 0; j < WIDTH; ++j) a[j] = fmaf(zv.y, wk[16 + j], a[j]);
        #pragma unroll
        for (int j = 0; j < WIDTH; ++j) a[j] = fmaf(zv.z, wk[32 + j], a[j]);
        #pragma unroll
        for (int j = 0; j < WIDTH; ++j) a[j] = fmaf(zv.w, wk[48 + j], a[j]);
    }

    // tanh + trace
    float tr = 0.0f;
    #pragma unroll
    for (int j = 0; j < WIDTH; ++j) {
        float th = fast_tanh(a[j]);
        a[j] = th;
        tr = fmaf(1.0f - th * th, ws[2064 + j], tr);
    }
    if (valid) dlog[row] = tr;            // 64 lanes x 4 B = 2 full lines

    // phase 2: dz = th @ uT in two 128-B halves, staged through the same tile.
    // Safe reuse: all lanes' phase-1 ds_reads precede these ds_writes in
    // program order, and same-wave DS is in-order.
    const float* uT = ws + 1024;
    float4* dzv = (float4*)dz;

    #pragma unroll
    for (int h = 0; h < 2; ++h) {
        #pragma unroll
        for (int c = 0; c < 8; ++c) {
            const int d0 = h * 32 + c * 4;
            float4 o = make_float4(0.f, 0.f, 0.f, 0.f);
            #pragma unroll
            for (int j = 0; j < WIDTH; ++j) {
                const float th = a[j];
                o.x = fmaf(th, uT[(d0 + 0) * 16 + j], o.x);
                o.y = fmaf(th, uT[(d0 + 1) * 16 + j], o.y);
                o.z = fmaf(th, uT[(d0 + 2) * 16 + j], o.z);
                o.w = fmaf(th, uT[(d0 + 3) * 16 + j], o.w);
            }
            ztile[l][c ^ (l & 7)] = o;    // stage own row's 128-B half
        }
        // transposed store: 8 instrs, each 8 consecutive rows x full 128-B line
        #pragma unroll
        for (int s = 0; s < 8; ++s) {
            const int r = 8 * s + (l >> 3);
            const float4 v = ztile[r][(l & 7) ^ (r & 7)];
            const int grow = base + r;
            if (grow < n)
                dzv[(size_t)grow * 16 + h * 8 + (l & 7)] = v;
        }
    }
}

extern "C" void kernel_launch(void* const* d_in, const int* in_sizes, int n_in,
                              void* d_out, int out_size, void* d_ws, size_t ws_size,
                              hipStream_t stream) {
    const float* t  = (const float*)d_in[0];
    const float* z  = (const float*)d_in[1];
    const float* W1 = (const float*)d_in[2];
    const float* b1 = (const float*)d_in[3];
    const float* W2 = (const float*)d_in[4];
    const float* b2 = (const float*)d_in[5];
    const float* W3 = (const float*)d_in[6];
    const float* b3 = (const float*)d_in[7];

    const int n = in_sizes[1] / IO_DIM;   // 500000
    float* ws   = (float*)d_ws;
    float* out  = (float*)d_out;
    float* dz   = out;
    float* dlog = out + (size_t)n * IO_DIM;

    cnf_prep<<<17, 128, 0, stream>>>(t, W1, b1, W2, b2, W3, b3, ws);

    const int grid = (n + 63) / 64;
    cnf_main<<<grid, 64, 0, stream>>>(z, ws, dz, dlog, n);
}